// Round 2
// baseline (780.920 us; speedup 1.0000x reference)
//
#include <hip/hip_runtime.h>
#include <math.h>

#define DD     512
#define NBATCH 16
#define SENC   1024
#define TTOK   2048
#define NHEAD  8
#define HDIM   64
#define NE     64

// ---------------- workspace layout (float element offsets) ----------------
#define WS_K1    0                           // 16*1024*512
#define WS_V1    (WS_K1 + NBATCH*SENC*DD)
#define WS_EMB0  (WS_V1 + NBATCH*SENC*DD)    // 64*512
#define WS_Q1    (WS_EMB0 + NE*DD)
#define WS_ATT1  (WS_Q1 + NE*DD)             // 16*64*512
#define WS_EMB1  (WS_ATT1 + NBATCH*NE*DD)
#define WS_Q2    (WS_EMB1 + NBATCH*NE*DD)
#define WS_K2    (WS_Q2 + NBATCH*NE*DD)
#define WS_V2    (WS_K2 + NBATCH*NE*DD)
#define WS_ATT2  (WS_V2 + NBATCH*NE*DD)
#define WS_YBUF  (WS_ATT2 + NBATCH*NE*DD)
#define WS_EMBF  (WS_YBUF + NBATCH*NE*DD)
#define WS_E2    (WS_EMBF + NBATCH*NE*DD)    // doubles: 16*64  (=2048 floats)
#define WS_LOSSP (WS_E2 + 2*NBATCH*NE)       // doubles: 256    (=512 floats)
#define WS_CNT   (WS_LOSSP + 2*256)          // ints: 64

// ---------------- output layout (float element offsets) ----------------
#define OUT_ZQ   0
#define OUT_LOSS (NBATCH*TTOK*DD)            // 16777216
#define OUT_PERP (OUT_LOSS + 1)
#define OUT_ENC  (OUT_PERP + 1)
#define OUT_IDX  (OUT_ENC + NBATCH*TTOK*NE)
#define OUT_EMB  (OUT_IDX + NBATCH*TTOK)

// =======================================================================
// PE + emb0:  emb0[p][c] = emb_table[p][c] + pe[p][c]
// pe computed in f64 then rounded -> matches numpy f32 path to ~1 ulp.
// =======================================================================
__global__ __launch_bounds__(256) void pe_emb0_k(const float* __restrict__ tab,
                                                 float* __restrict__ emb0)
{
    int p = blockIdx.x;
    for (int c = threadIdx.x; c < DD; c += 256) {
        int ie = c & ~1;
        float denom = (float)pow(10000.0, (double)ie / 512.0);
        float ang = (float)p / denom;            // f32 division, matches np
        double v = (c & 1) ? cos((double)ang) : sin((double)ang);
        emb0[p * DD + c] = tab[p * DD + c] + (float)v;
    }
}

// =======================================================================
// Generic f32 GEMM + bias:  C_o = A(M x 512) @ W_o(512 x 512) + b_o
// 64x64 tile, BK=32, 256 threads, 4x4 microtile, NOUT fused outputs.
// =======================================================================
template <int NOUT>
__global__ __launch_bounds__(256) void gemm_bias_k(
    const float* __restrict__ A,
    const float* __restrict__ W0, const float* __restrict__ B0, float* __restrict__ C0,
    const float* __restrict__ W1, const float* __restrict__ B1, float* __restrict__ C1,
    const float* __restrict__ W2, const float* __restrict__ B2, float* __restrict__ C2)
{
    __shared__ float As[32][64];          // [k][m]
    __shared__ float Ws[NOUT][32][64];    // [k][n]
    const int m0 = blockIdx.x * 64;
    const int n0 = blockIdx.y * 64;
    const int tid = threadIdx.x;
    const int tx = tid & 15, ty = tid >> 4;

    float acc[NOUT][4][4];
#pragma unroll
    for (int o = 0; o < NOUT; ++o)
#pragma unroll
        for (int i = 0; i < 4; ++i)
#pragma unroll
            for (int j = 0; j < 4; ++j) acc[o][i][j] = 0.f;

    const float* Wp[3] = {W0, W1, W2};

    for (int kk = 0; kk < DD; kk += 32) {
        __syncthreads();
#pragma unroll
        for (int l = 0; l < 2; ++l) {
            int fid = l * 256 + tid;          // 512 float4 of A tile
            int row = fid >> 3, c4 = fid & 7;
            float4 v = *reinterpret_cast<const float4*>(&A[(size_t)(m0 + row) * DD + kk + c4 * 4]);
            As[c4 * 4 + 0][row] = v.x;
            As[c4 * 4 + 1][row] = v.y;
            As[c4 * 4 + 2][row] = v.z;
            As[c4 * 4 + 3][row] = v.w;
        }
#pragma unroll
        for (int o = 0; o < NOUT; ++o) {
#pragma unroll
            for (int l = 0; l < 2; ++l) {
                int fid = l * 256 + tid;      // 512 float4 of W tile
                int kr = fid >> 4, c4 = fid & 15;
                *reinterpret_cast<float4*>(&Ws[o][kr][c4 * 4]) =
                    *reinterpret_cast<const float4*>(&Wp[o][(size_t)(kk + kr) * DD + n0 + c4 * 4]);
            }
        }
        __syncthreads();
#pragma unroll
        for (int k = 0; k < 32; ++k) {
            float4 av = *reinterpret_cast<const float4*>(&As[k][ty * 4]);
            float a[4] = {av.x, av.y, av.z, av.w};
#pragma unroll
            for (int o = 0; o < NOUT; ++o) {
                float4 wv = *reinterpret_cast<const float4*>(&Ws[o][k][tx * 4]);
#pragma unroll
                for (int i = 0; i < 4; ++i) {
                    acc[o][i][0] = fmaf(a[i], wv.x, acc[o][i][0]);
                    acc[o][i][1] = fmaf(a[i], wv.y, acc[o][i][1]);
                    acc[o][i][2] = fmaf(a[i], wv.z, acc[o][i][2]);
                    acc[o][i][3] = fmaf(a[i], wv.w, acc[o][i][3]);
                }
            }
        }
    }
    float* Cp[3] = {C0, C1, C2};
    const float* Bp[3] = {B0, B1, B2};
#pragma unroll
    for (int o = 0; o < NOUT; ++o) {
#pragma unroll
        for (int i = 0; i < 4; ++i) {
            int row = m0 + ty * 4 + i;
#pragma unroll
            for (int j = 0; j < 4; ++j) {
                int col = n0 + tx * 4 + j;
                Cp[o][(size_t)row * DD + col] = acc[o][i][j] + Bp[o][col];
            }
        }
    }
}

// =======================================================================
// MHA core: one block per (b,h). 64 query rows, online softmax over slen.
// thread = (row = tid>>2, c4 = tid&3); each thread owns 16 output cols.
// =======================================================================
__global__ __launch_bounds__(256) void attn_k(
    const float* __restrict__ q, int q_shared,
    const float* __restrict__ kmat, const float* __restrict__ vmat,
    float* __restrict__ outp, int slen)
{
    __shared__ float qs[64][68];
    __shared__ float kst[64][68]; // [e][j] (transposed)
    __shared__ float vs[64][68];  // [j][c]
    int b = blockIdx.x >> 3, h = blockIdx.x & 7;
    int tid = threadIdx.x;
    const float* qb = q + (q_shared ? (size_t)0 : (size_t)b * 64 * DD);
    const float* kb = kmat + (size_t)b * slen * DD;
    const float* vb = vmat + (size_t)b * slen * DD;

#pragma unroll
    for (int l = 0; l < 4; ++l) {
        int fid = l * 256 + tid;
        int r = fid >> 4, c4 = fid & 15;
        *reinterpret_cast<float4*>(&qs[r][c4 * 4]) =
            *reinterpret_cast<const float4*>(&qb[(size_t)r * DD + h * HDIM + c4 * 4]);
    }
    const int row = tid >> 2, c4 = tid & 3;
    float acc[16];
#pragma unroll
    for (int i = 0; i < 16; ++i) acc[i] = 0.f;
    float m_run = -INFINITY, l_run = 0.f;

    for (int s0 = 0; s0 < slen; s0 += 64) {
        __syncthreads();
#pragma unroll
        for (int l = 0; l < 4; ++l) {
            int fid = l * 256 + tid;
            int r = fid >> 4, cc = fid & 15;
            float4 t4 = *reinterpret_cast<const float4*>(&kb[(size_t)(s0 + r) * DD + h * HDIM + cc * 4]);
            kst[cc * 4 + 0][r] = t4.x;
            kst[cc * 4 + 1][r] = t4.y;
            kst[cc * 4 + 2][r] = t4.z;
            kst[cc * 4 + 3][r] = t4.w;
            *reinterpret_cast<float4*>(&vs[r][cc * 4]) =
                *reinterpret_cast<const float4*>(&vb[(size_t)(s0 + r) * DD + h * HDIM + cc * 4]);
        }
        __syncthreads();

        float p[16];
#pragma unroll
        for (int i = 0; i < 16; ++i) p[i] = 0.f;
#pragma unroll 4
        for (int e = 0; e < 64; ++e) {
            float qv = qs[row][e];
#pragma unroll
            for (int j4 = 0; j4 < 4; ++j4) {
                float4 k4 = *reinterpret_cast<const float4*>(&kst[e][c4 * 16 + j4 * 4]);
                p[j4 * 4 + 0] = fmaf(qv, k4.x, p[j4 * 4 + 0]);
                p[j4 * 4 + 1] = fmaf(qv, k4.y, p[j4 * 4 + 1]);
                p[j4 * 4 + 2] = fmaf(qv, k4.z, p[j4 * 4 + 2]);
                p[j4 * 4 + 3] = fmaf(qv, k4.w, p[j4 * 4 + 3]);
            }
        }
#pragma unroll
        for (int i = 0; i < 16; ++i) p[i] *= 0.125f;   // / sqrt(64), exact
        float mx = p[0];
#pragma unroll
        for (int i = 1; i < 16; ++i) mx = fmaxf(mx, p[i]);
        mx = fmaxf(mx, __shfl_xor(mx, 1));
        mx = fmaxf(mx, __shfl_xor(mx, 2));
        float m_new = fmaxf(m_run, mx);
        float scale = expf(m_run - m_new);             // 0 on first tile
        float lsum = 0.f;
#pragma unroll
        for (int i = 0; i < 16; ++i) { p[i] = expf(p[i] - m_new); lsum += p[i]; }
        lsum += __shfl_xor(lsum, 1);
        lsum += __shfl_xor(lsum, 2);
        l_run = l_run * scale + lsum;
        m_run = m_new;
#pragma unroll
        for (int i = 0; i < 16; ++i) acc[i] *= scale;

#pragma unroll 16
        for (int j = 0; j < 64; ++j) {
            float pv = __shfl(p[j & 15], j >> 4, 4);   // owner lane in quad
#pragma unroll
            for (int u = 0; u < 4; ++u) {
                float4 v4 = *reinterpret_cast<const float4*>(&vs[j][c4 * 16 + u * 4]);
                acc[u * 4 + 0] = fmaf(pv, v4.x, acc[u * 4 + 0]);
                acc[u * 4 + 1] = fmaf(pv, v4.y, acc[u * 4 + 1]);
                acc[u * 4 + 2] = fmaf(pv, v4.z, acc[u * 4 + 2]);
                acc[u * 4 + 3] = fmaf(pv, v4.w, acc[u * 4 + 3]);
            }
        }
    }
#pragma unroll
    for (int i = 0; i < 16; ++i) acc[i] /= l_run;
#pragma unroll
    for (int u = 0; u < 4; ++u) {
        float4 o4 = {acc[u * 4 + 0], acc[u * 4 + 1], acc[u * 4 + 2], acc[u * 4 + 3]};
        *reinterpret_cast<float4*>(&outp[((size_t)b * 64 + row) * DD + h * HDIM + c4 * 16 + u * 4]) = o4;
    }
}

// =======================================================================
// LayerNorm of (res + y), optional duplicate write + sum-of-squares (f64)
// =======================================================================
__device__ __forceinline__ float block_sum256(float v, float* sb)
{
#pragma unroll
    for (int off = 32; off; off >>= 1) v += __shfl_down(v, off);
    __syncthreads();
    if ((threadIdx.x & 63) == 0) sb[threadIdx.x >> 6] = v;
    __syncthreads();
    return (sb[0] + sb[1]) + (sb[2] + sb[3]);
}

__global__ __launch_bounds__(256) void ln_k(
    const float* __restrict__ res, int res_shared, const float* __restrict__ y,
    const float* __restrict__ g, const float* __restrict__ bb,
    float* __restrict__ out, float* __restrict__ out2, double* __restrict__ e2)
{
    __shared__ float sbuf[4];
    __shared__ double dbuf[4];
    int row = blockIdx.x;
    int t = threadIdx.x;
    const float* rp = res + (size_t)(res_shared ? (row & 63) : row) * DD;
    const float* yp = y + (size_t)row * DD;
    float x0 = rp[t] + yp[t];
    float x1 = rp[t + 256] + yp[t + 256];
    float m = block_sum256(x0 + x1, sbuf) / 512.0f;
    float d0 = x0 - m, d1 = x1 - m;
    float v = block_sum256(d0 * d0 + d1 * d1, sbuf) / 512.0f;
    float s = sqrtf(v + 1e-5f);
    float o0 = d0 / s * g[t] + bb[t];
    float o1 = d1 / s * g[t + 256] + bb[t + 256];
    out[(size_t)row * DD + t] = o0;
    out[(size_t)row * DD + t + 256] = o1;
    if (out2) {
        out2[(size_t)row * DD + t] = o0;
        out2[(size_t)row * DD + t + 256] = o1;
    }
    if (e2) {
        double sd = (double)o0 * o0 + (double)o1 * o1;
#pragma unroll
        for (int off = 32; off; off >>= 1) sd += __shfl_down(sd, off);
        if ((t & 63) == 0) dbuf[t >> 6] = sd;
        __syncthreads();
        if (t == 0) e2[row] = (dbuf[0] + dbuf[1]) + (dbuf[2] + dbuf[3]);
    }
}

// =======================================================================
// VQ: per z-row argmin_k (e2_k - 2 z.e_k) in f64; writes zq/enc/idx;
// accumulates loss partials (deterministic) and code counts (int atomics).
// emb staged in LDS with XOR-swizzled layout (conflict-free quad reads).
// thread = (c = tid>>2 code, p = tid&3 dim-quarter)
// =======================================================================
__global__ __launch_bounds__(256) void vq_k(
    const float* __restrict__ z, const float* __restrict__ emb,
    const double* __restrict__ e2,
    float* __restrict__ zq, float* __restrict__ enc, float* __restrict__ idxo,
    double* __restrict__ lossp, int* __restrict__ counts)
{
    __shared__ float es[64 * 513];
    __shared__ float zs[4 * 516];
    __shared__ double sc[4][64];
    __shared__ double dred[4];
    __shared__ int cnt_s[64];

    int bid = blockIdx.x;
    int b = bid >> 4;
    int t0 = (bid & 15) * 128;
    int tid = threadIdx.x;
    int c = tid >> 2, p = tid & 3;

    // stage emb[b] (64 x 512) swizzled: addr = c*513 + pp*128 + (ix ^ (pp<<3))
    for (int l = 0; l < 32; ++l) {
        int fid = l * 256 + tid;      // 8192 float4
        int cc = fid >> 7;
        int x4 = fid & 127;
        float4 t4 = *reinterpret_cast<const float4*>(&emb[((size_t)b * 64 + cc) * DD + x4 * 4]);
        int x = x4 * 4;
        int pp = x >> 7, ix = x & 127;
        int base = cc * 513 + pp * 128 + (ix ^ (pp << 3));
        es[base + 0] = t4.x; es[base + 1] = t4.y; es[base + 2] = t4.z; es[base + 3] = t4.w;
    }
    if (tid < 64) cnt_s[tid] = 0;
    double lsum = 0.0;
    __syncthreads();
    double e2c = e2[b * 64 + c];

    for (int g0 = 0; g0 < 128; g0 += 4) {
        __syncthreads();
#pragma unroll
        for (int l = 0; l < 2; ++l) {
            int fid = l * 256 + tid;  // 512 float4
            int r = fid >> 7, x4 = fid & 127;
            float4 t4 = *reinterpret_cast<const float4*>(&z[((size_t)b * TTOK + t0 + g0 + r) * DD + x4 * 4]);
            int x = x4 * 4;
            int pp = x >> 7, ix = x & 127;
            int base = r * 516 + pp * 128 + (ix ^ (pp << 3));
            zs[base + 0] = t4.x; zs[base + 1] = t4.y; zs[base + 2] = t4.z; zs[base + 3] = t4.w;
        }
        __syncthreads();

        double a0 = 0, a1 = 0, a2 = 0, a3 = 0;
        int ebase = c * 513 + p * 128;
        int zoff = p * 128;
#pragma unroll 8
        for (int i = 0; i < 128; ++i) {
            int sw = i ^ (p << 3);
            double ev = (double)es[ebase + sw];
            a0 = fma((double)zs[0 * 516 + zoff + sw], ev, a0);
            a1 = fma((double)zs[1 * 516 + zoff + sw], ev, a1);
            a2 = fma((double)zs[2 * 516 + zoff + sw], ev, a2);
            a3 = fma((double)zs[3 * 516 + zoff + sw], ev, a3);
        }
        a0 += __shfl_xor(a0, 1); a0 += __shfl_xor(a0, 2);
        a1 += __shfl_xor(a1, 1); a1 += __shfl_xor(a1, 2);
        a2 += __shfl_xor(a2, 1); a2 += __shfl_xor(a2, 2);
        a3 += __shfl_xor(a3, 1); a3 += __shfl_xor(a3, 2);
        if (p == 0) {
            sc[0][c] = e2c - 2.0 * a0;
            sc[1][c] = e2c - 2.0 * a1;
            sc[2][c] = e2c - 2.0 * a2;
            sc[3][c] = e2c - 2.0 * a3;
        }
        __syncthreads();

        // argmin (first-index tie-break): wave w handles row w
        int w = tid >> 6, lane = tid & 63;
        double v = sc[w][lane];
        int ki = lane;
#pragma unroll
        for (int off = 32; off; off >>= 1) {
            double ov = __shfl_xor(v, off);
            int oi = __shfl_xor(ki, off);
            if (ov < v || (ov == v && oi < ki)) { v = ov; ki = oi; }
        }
        int km = ki;
        size_t grow = (size_t)b * TTOK + t0 + g0 + w;
        if (lane == 0) {
            idxo[grow] = (float)km;
            atomicAdd(&cnt_s[km], 1);
        }
        enc[grow * 64 + lane] = (lane == km) ? 1.0f : 0.0f;

        int kb2 = km * 513;
        int zb2 = w * 516;
#pragma unroll
        for (int q4 = 0; q4 < 2; ++q4) {
            float ov[4];
#pragma unroll
            for (int u = 0; u < 4; ++u) {
                int x = lane * 8 + q4 * 4 + u;
                int pp = x >> 7, ix = x & 127;
                int sw = pp * 128 + (ix ^ (pp << 3));
                float ev = es[kb2 + sw];
                float zv = zs[zb2 + sw];
                float d = ev - zv;            // np: z_q - z
                lsum += (double)d * d;
                ov[u] = zv + d;               // np: z + sg(z_q - z)
            }
            float4 o4 = {ov[0], ov[1], ov[2], ov[3]};
            *reinterpret_cast<float4*>(&zq[grow * DD + lane * 8 + q4 * 4]) = o4;
        }
    }
    // deterministic block loss reduce
#pragma unroll
    for (int off = 32; off; off >>= 1) lsum += __shfl_down(lsum, off);
    if ((tid & 63) == 0) dred[tid >> 6] = lsum;
    __syncthreads();
    if (tid == 0) lossp[bid] = (dred[0] + dred[1]) + (dred[2] + dred[3]);
    if (tid < 64 && cnt_s[tid]) atomicAdd(&counts[tid], cnt_s[tid]);
}

// =======================================================================
// Finalize: loss (sequential f64 sum of 256 partials) + perplexity
// =======================================================================
__global__ void fin_k(const double* __restrict__ lossp, const int* __restrict__ counts,
                      float* __restrict__ loss_out, float* __restrict__ perp_out)
{
    int tid = threadIdx.x;  // 64 threads
    if (tid == 0) {
        double tot = 0.0;
        for (int i = 0; i < 256; ++i) tot += lossp[i];
        loss_out[0] = (float)(1.5 * tot / 16777216.0);   // (BETA+1)*mean
    }
    float e = counts[tid] / 32768.0f;
    float term = e * logf(e + 1e-10f);
#pragma unroll
    for (int off = 32; off; off >>= 1) term += __shfl_down(term, off);
    if (tid == 0) perp_out[0] = expf(-term);
}

// =======================================================================
extern "C" void kernel_launch(void* const* d_in, const int* in_sizes, int n_in,
                              void* d_out, int out_size, void* d_ws, size_t ws_size,
                              hipStream_t stream)
{
    (void)in_sizes; (void)n_in; (void)out_size; (void)ws_size;
    const float* x_enc = (const float*)d_in[0];
    const float* z     = (const float*)d_in[1];
    const float* tab   = (const float*)d_in[2];
    const float* wq1 = (const float*)d_in[3];  const float* bq1 = (const float*)d_in[4];
    const float* wk1 = (const float*)d_in[5];  const float* bk1 = (const float*)d_in[6];
    const float* wv1 = (const float*)d_in[7];  const float* bv1 = (const float*)d_in[8];
    const float* wo1 = (const float*)d_in[9];  const float* bo1 = (const float*)d_in[10];
    const float* wq2 = (const float*)d_in[11]; const float* bq2 = (const float*)d_in[12];
    const float* wk2 = (const float*)d_in[13]; const float* bk2 = (const float*)d_in[14];
    const float* wv2 = (const float*)d_in[15]; const float* bv2 = (const float*)d_in[16];
    const float* wo2 = (const float*)d_in[17]; const float* bo2 = (const float*)d_in[18];
    const float* ln2g = (const float*)d_in[19]; const float* ln2b = (const float*)d_in[20];
    const float* ln1g = (const float*)d_in[21]; const float* ln1b = (const float*)d_in[22];

    float* ws  = (float*)d_ws;
    float* out = (float*)d_out;

    float* k1   = ws + WS_K1;
    float* v1   = ws + WS_V1;
    float* emb0 = ws + WS_EMB0;
    float* q1   = ws + WS_Q1;
    float* att1 = ws + WS_ATT1;
    float* emb1 = ws + WS_EMB1;
    float* q2   = ws + WS_Q2;
    float* k2   = ws + WS_K2;
    float* v2   = ws + WS_V2;
    float* att2 = ws + WS_ATT2;
    float* ybuf = ws + WS_YBUF;
    float* embf = ws + WS_EMBF;
    double* e2    = (double*)(ws + WS_E2);
    double* lossp = (double*)(ws + WS_LOSSP);
    int*    cnts  = (int*)(ws + WS_CNT);

    hipMemsetAsync(cnts, 0, NE * sizeof(int), stream);

    pe_emb0_k<<<64, 256, 0, stream>>>(tab, emb0);

    gemm_bias_k<1><<<dim3(1, 8), 256, 0, stream>>>(emb0, wq1, bq1, q1,
                                                   nullptr, nullptr, nullptr,
                                                   nullptr, nullptr, nullptr);
    gemm_bias_k<2><<<dim3(256, 8), 256, 0, stream>>>(x_enc, wk1, bk1, k1,
                                                     wv1, bv1, v1,
                                                     nullptr, nullptr, nullptr);
    attn_k<<<128, 256, 0, stream>>>(q1, 1, k1, v1, att1, SENC);

    gemm_bias_k<1><<<dim3(16, 8), 256, 0, stream>>>(att1, wo1, bo1, ybuf,
                                                    nullptr, nullptr, nullptr,
                                                    nullptr, nullptr, nullptr);
    ln_k<<<1024, 256, 0, stream>>>(emb0, 1, ybuf, ln1g, ln1b, emb1, nullptr, nullptr);

    gemm_bias_k<3><<<dim3(16, 8), 256, 0, stream>>>(emb1, wq2, bq2, q2,
                                                    wk2, bk2, k2,
                                                    wv2, bv2, v2);
    attn_k<<<128, 256, 0, stream>>>(q2, 0, k2, v2, att2, 64);

    gemm_bias_k<1><<<dim3(16, 8), 256, 0, stream>>>(att2, wo2, bo2, ybuf,
                                                    nullptr, nullptr, nullptr,
                                                    nullptr, nullptr, nullptr);
    ln_k<<<1024, 256, 0, stream>>>(emb1, 0, ybuf, ln2g, ln2b, embf, out + OUT_EMB, e2);

    vq_k<<<256, 256, 0, stream>>>(z, embf, e2,
                                  out + OUT_ZQ, out + OUT_ENC, out + OUT_IDX,
                                  lossp, cnts);
    fin_k<<<1, 64, 0, stream>>>(lossp, cnts, out + OUT_LOSS, out + OUT_PERP);
}

// Round 4
// 610.103 us; speedup vs baseline: 1.2800x; 1.2800x over previous
//
#include <hip/hip_runtime.h>
#include <math.h>

#define DD     512
#define NBATCH 16
#define SENC   1024
#define TTOK   2048
#define NHEAD  8
#define HDIM   64
#define NE     64

// ---------------- workspace layout (float element offsets) ----------------
#define WS_K1    0                           // 16*1024*512
#define WS_V1    (WS_K1 + NBATCH*SENC*DD)
#define WS_EMB0  (WS_V1 + NBATCH*SENC*DD)    // 64*512
#define WS_Q1    (WS_EMB0 + NE*DD)
#define WS_ATT1  (WS_Q1 + NE*DD)             // 16*64*512
#define WS_EMB1  (WS_ATT1 + NBATCH*NE*DD)
#define WS_Q2    (WS_EMB1 + NBATCH*NE*DD)
#define WS_K2    (WS_Q2 + NBATCH*NE*DD)
#define WS_V2    (WS_K2 + NBATCH*NE*DD)
#define WS_ATT2  (WS_V2 + NBATCH*NE*DD)
#define WS_YBUF  (WS_ATT2 + NBATCH*NE*DD)
#define WS_EMBF  (WS_YBUF + NBATCH*NE*DD)
#define WS_E2    (WS_EMBF + NBATCH*NE*DD)    // doubles: 16*64  (=2048 floats)
#define WS_LOSSP (WS_E2 + 2*NBATCH*NE)       // doubles: 512    (=1024 floats)
#define WS_CNT   (WS_LOSSP + 2*512)          // ints: 64

// ---------------- output layout (float element offsets) ----------------
#define OUT_ZQ   0
#define OUT_LOSS (NBATCH*TTOK*DD)            // 16777216
#define OUT_PERP (OUT_LOSS + 1)
#define OUT_ENC  (OUT_PERP + 1)
#define OUT_IDX  (OUT_ENC + NBATCH*TTOK*NE)
#define OUT_EMB  (OUT_IDX + NBATCH*TTOK)

// =======================================================================
// PE + emb0  (UNCHANGED — stage A must stay bit-identical)
// =======================================================================
__global__ __launch_bounds__(256) void pe_emb0_k(const float* __restrict__ tab,
                                                 float* __restrict__ emb0)
{
    int p = blockIdx.x;
    for (int c = threadIdx.x; c < DD; c += 256) {
        int ie = c & ~1;
        float denom = (float)pow(10000.0, (double)ie / 512.0);
        float ang = (float)p / denom;            // f32 division, matches np
        double v = (c & 1) ? cos((double)ang) : sin((double)ang);
        emb0[p * DD + c] = tab[p * DD + c] + (float)v;
    }
}

// =======================================================================
// Generic f32 GEMM + bias (UNCHANGED)
// =======================================================================
template <int NOUT>
__global__ __launch_bounds__(256) void gemm_bias_k(
    const float* __restrict__ A,
    const float* __restrict__ W0, const float* __restrict__ B0, float* __restrict__ C0,
    const float* __restrict__ W1, const float* __restrict__ B1, float* __restrict__ C1,
    const float* __restrict__ W2, const float* __restrict__ B2, float* __restrict__ C2)
{
    __shared__ float As[32][64];          // [k][m]
    __shared__ float Ws[NOUT][32][64];    // [k][n]
    const int m0 = blockIdx.x * 64;
    const int n0 = blockIdx.y * 64;
    const int tid = threadIdx.x;
    const int tx = tid & 15, ty = tid >> 4;

    float acc[NOUT][4][4];
#pragma unroll
    for (int o = 0; o < NOUT; ++o)
#pragma unroll
        for (int i = 0; i < 4; ++i)
#pragma unroll
            for (int j = 0; j < 4; ++j) acc[o][i][j] = 0.f;

    const float* Wp[3] = {W0, W1, W2};

    for (int kk = 0; kk < DD; kk += 32) {
        __syncthreads();
#pragma unroll
        for (int l = 0; l < 2; ++l) {
            int fid = l * 256 + tid;          // 512 float4 of A tile
            int row = fid >> 3, c4 = fid & 7;
            float4 v = *reinterpret_cast<const float4*>(&A[(size_t)(m0 + row) * DD + kk + c4 * 4]);
            As[c4 * 4 + 0][row] = v.x;
            As[c4 * 4 + 1][row] = v.y;
            As[c4 * 4 + 2][row] = v.z;
            As[c4 * 4 + 3][row] = v.w;
        }
#pragma unroll
        for (int o = 0; o < NOUT; ++o) {
#pragma unroll
            for (int l = 0; l < 2; ++l) {
                int fid = l * 256 + tid;      // 512 float4 of W tile
                int kr = fid >> 4, c4 = fid & 15;
                *reinterpret_cast<float4*>(&Ws[o][kr][c4 * 4]) =
                    *reinterpret_cast<const float4*>(&Wp[o][(size_t)(kk + kr) * DD + n0 + c4 * 4]);
            }
        }
        __syncthreads();
#pragma unroll
        for (int k = 0; k < 32; ++k) {
            float4 av = *reinterpret_cast<const float4*>(&As[k][ty * 4]);
            float a[4] = {av.x, av.y, av.z, av.w};
#pragma unroll
            for (int o = 0; o < NOUT; ++o) {
                float4 wv = *reinterpret_cast<const float4*>(&Ws[o][k][tx * 4]);
#pragma unroll
                for (int i = 0; i < 4; ++i) {
                    acc[o][i][0] = fmaf(a[i], wv.x, acc[o][i][0]);
                    acc[o][i][1] = fmaf(a[i], wv.y, acc[o][i][1]);
                    acc[o][i][2] = fmaf(a[i], wv.z, acc[o][i][2]);
                    acc[o][i][3] = fmaf(a[i], wv.w, acc[o][i][3]);
                }
            }
        }
    }
    float* Cp[3] = {C0, C1, C2};
    const float* Bp[3] = {B0, B1, B2};
#pragma unroll
    for (int o = 0; o < NOUT; ++o) {
#pragma unroll
        for (int i = 0; i < 4; ++i) {
            int row = m0 + ty * 4 + i;
#pragma unroll
            for (int j = 0; j < 4; ++j) {
                int col = n0 + tx * 4 + j;
                Cp[o][(size_t)row * DD + col] = acc[o][i][j] + Bp[o][col];
            }
        }
    }
}

// =======================================================================
// MHA core (UNCHANGED)
// =======================================================================
__global__ __launch_bounds__(256) void attn_k(
    const float* __restrict__ q, int q_shared,
    const float* __restrict__ kmat, const float* __restrict__ vmat,
    float* __restrict__ outp, int slen)
{
    __shared__ float qs[64][68];
    __shared__ float kst[64][68]; // [e][j] (transposed)
    __shared__ float vs[64][68];  // [j][c]
    int b = blockIdx.x >> 3, h = blockIdx.x & 7;
    int tid = threadIdx.x;
    const float* qb = q + (q_shared ? (size_t)0 : (size_t)b * 64 * DD);
    const float* kb = kmat + (size_t)b * slen * DD;
    const float* vb = vmat + (size_t)b * slen * DD;

#pragma unroll
    for (int l = 0; l < 4; ++l) {
        int fid = l * 256 + tid;
        int r = fid >> 4, c4 = fid & 15;
        *reinterpret_cast<float4*>(&qs[r][c4 * 4]) =
            *reinterpret_cast<const float4*>(&qb[(size_t)r * DD + h * HDIM + c4 * 4]);
    }
    const int row = tid >> 2, c4 = tid & 3;
    float acc[16];
#pragma unroll
    for (int i = 0; i < 16; ++i) acc[i] = 0.f;
    float m_run = -INFINITY, l_run = 0.f;

    for (int s0 = 0; s0 < slen; s0 += 64) {
        __syncthreads();
#pragma unroll
        for (int l = 0; l < 4; ++l) {
            int fid = l * 256 + tid;
            int r = fid >> 4, cc = fid & 15;
            float4 t4 = *reinterpret_cast<const float4*>(&kb[(size_t)(s0 + r) * DD + h * HDIM + cc * 4]);
            kst[cc * 4 + 0][r] = t4.x;
            kst[cc * 4 + 1][r] = t4.y;
            kst[cc * 4 + 2][r] = t4.z;
            kst[cc * 4 + 3][r] = t4.w;
            *reinterpret_cast<float4*>(&vs[r][cc * 4]) =
                *reinterpret_cast<const float4*>(&vb[(size_t)(s0 + r) * DD + h * HDIM + cc * 4]);
        }
        __syncthreads();

        float p[16];
#pragma unroll
        for (int i = 0; i < 16; ++i) p[i] = 0.f;
#pragma unroll 4
        for (int e = 0; e < 64; ++e) {
            float qv = qs[row][e];
#pragma unroll
            for (int j4 = 0; j4 < 4; ++j4) {
                float4 k4 = *reinterpret_cast<const float4*>(&kst[e][c4 * 16 + j4 * 4]);
                p[j4 * 4 + 0] = fmaf(qv, k4.x, p[j4 * 4 + 0]);
                p[j4 * 4 + 1] = fmaf(qv, k4.y, p[j4 * 4 + 1]);
                p[j4 * 4 + 2] = fmaf(qv, k4.z, p[j4 * 4 + 2]);
                p[j4 * 4 + 3] = fmaf(qv, k4.w, p[j4 * 4 + 3]);
            }
        }
#pragma unroll
        for (int i = 0; i < 16; ++i) p[i] *= 0.125f;   // / sqrt(64), exact
        float mx = p[0];
#pragma unroll
        for (int i = 1; i < 16; ++i) mx = fmaxf(mx, p[i]);
        mx = fmaxf(mx, __shfl_xor(mx, 1));
        mx = fmaxf(mx, __shfl_xor(mx, 2));
        float m_new = fmaxf(m_run, mx);
        float scale = expf(m_run - m_new);             // 0 on first tile
        float lsum = 0.f;
#pragma unroll
        for (int i = 0; i < 16; ++i) { p[i] = expf(p[i] - m_new); lsum += p[i]; }
        lsum += __shfl_xor(lsum, 1);
        lsum += __shfl_xor(lsum, 2);
        l_run = l_run * scale + lsum;
        m_run = m_new;
#pragma unroll
        for (int i = 0; i < 16; ++i) acc[i] *= scale;

#pragma unroll 16
        for (int j = 0; j < 64; ++j) {
            float pv = __shfl(p[j & 15], j >> 4, 4);   // owner lane in quad
#pragma unroll
            for (int u = 0; u < 4; ++u) {
                float4 v4 = *reinterpret_cast<const float4*>(&vs[j][c4 * 16 + u * 4]);
                acc[u * 4 + 0] = fmaf(pv, v4.x, acc[u * 4 + 0]);
                acc[u * 4 + 1] = fmaf(pv, v4.y, acc[u * 4 + 1]);
                acc[u * 4 + 2] = fmaf(pv, v4.z, acc[u * 4 + 2]);
                acc[u * 4 + 3] = fmaf(pv, v4.w, acc[u * 4 + 3]);
            }
        }
    }
#pragma unroll
    for (int i = 0; i < 16; ++i) acc[i] /= l_run;
#pragma unroll
    for (int u = 0; u < 4; ++u) {
        float4 o4 = {acc[u * 4 + 0], acc[u * 4 + 1], acc[u * 4 + 2], acc[u * 4 + 3]};
        *reinterpret_cast<float4*>(&outp[((size_t)b * 64 + row) * DD + h * HDIM + c4 * 16 + u * 4]) = o4;
    }
}

// =======================================================================
// LayerNorm (UNCHANGED)
// =======================================================================
__device__ __forceinline__ float block_sum256(float v, float* sb)
{
#pragma unroll
    for (int off = 32; off; off >>= 1) v += __shfl_down(v, off);
    __syncthreads();
    if ((threadIdx.x & 63) == 0) sb[threadIdx.x >> 6] = v;
    __syncthreads();
    return (sb[0] + sb[1]) + (sb[2] + sb[3]);
}

__global__ __launch_bounds__(256) void ln_k(
    const float* __restrict__ res, int res_shared, const float* __restrict__ y,
    const float* __restrict__ g, const float* __restrict__ bb,
    float* __restrict__ out, float* __restrict__ out2, double* __restrict__ e2)
{
    __shared__ float sbuf[4];
    __shared__ double dbuf[4];
    int row = blockIdx.x;
    int t = threadIdx.x;
    const float* rp = res + (size_t)(res_shared ? (row & 63) : row) * DD;
    const float* yp = y + (size_t)row * DD;
    float x0 = rp[t] + yp[t];
    float x1 = rp[t + 256] + yp[t + 256];
    float m = block_sum256(x0 + x1, sbuf) / 512.0f;
    float d0 = x0 - m, d1 = x1 - m;
    float v = block_sum256(d0 * d0 + d1 * d1, sbuf) / 512.0f;
    float s = sqrtf(v + 1e-5f);
    float o0 = d0 / s * g[t] + bb[t];
    float o1 = d1 / s * g[t + 256] + bb[t + 256];
    out[(size_t)row * DD + t] = o0;
    out[(size_t)row * DD + t + 256] = o1;
    if (out2) {
        out2[(size_t)row * DD + t] = o0;
        out2[(size_t)row * DD + t + 256] = o1;
    }
    if (e2) {
        double sd = (double)o0 * o0 + (double)o1 * o1;
#pragma unroll
        for (int off = 32; off; off >>= 1) sd += __shfl_down(sd, off);
        if ((t & 63) == 0) dbuf[t >> 6] = sd;
        __syncthreads();
        if (t == 0) e2[row] = (dbuf[0] + dbuf[1]) + (dbuf[2] + dbuf[3]);
    }
}

// =======================================================================
// VQ rebuilt as K-tiled GEMM (f64 accumulate kept — true-ordering argmin).
// Grid: 512 blocks (16 b × 32 row-tiles), 512 threads.
// Block: 64 z-rows × 64 codes; BK=32; LDS ~18 KB (vs 139 KB before).
// Thread (tx=tid&15, ty=tid>>4): rows {ty*2, ty*2+1} × codes {tx*4..+3}.
// Phase 2 (zq/enc/idx/loss) gathers z & emb straight from global (L2-hot).
// =======================================================================
__global__ __launch_bounds__(512) void vq_k(
    const float* __restrict__ z, const float* __restrict__ emb,
    const double* __restrict__ e2,
    float* __restrict__ zq, float* __restrict__ enc, float* __restrict__ idxo,
    double* __restrict__ lossp, int* __restrict__ counts)
{
    __shared__ float zs[32][68];   // [k][row]   272B row stride (16B-aligned)
    __shared__ float es[32][68];   // [k][code]
    __shared__ int   kms[64];
    __shared__ double dred[8];
    __shared__ int   cnt_s[64];

    const int bid = blockIdx.x;
    const int b   = bid >> 5;            // 32 row-tiles per batch
    const int m0  = (bid & 31) * 64;
    const int tid = threadIdx.x;
    const int tx  = tid & 15, ty = tid >> 4;      // ty 0..31

    const float* zb = z   + ((size_t)b * TTOK + m0) * DD;
    const float* eb = emb + (size_t)b * NE * DD;

    double acc[2][4];
#pragma unroll
    for (int r = 0; r < 2; ++r)
#pragma unroll
        for (int j = 0; j < 4; ++j) acc[r][j] = 0.0;

    const int lrow = tid >> 3, lc4 = tid & 7;     // staging indices

    for (int kk = 0; kk < DD; kk += 32) {
        __syncthreads();
        {   // z tile: 64 rows x 32 k, transposed to [k][row]
            float4 t4 = *reinterpret_cast<const float4*>(&zb[(size_t)lrow * DD + kk + lc4 * 4]);
            zs[lc4 * 4 + 0][lrow] = t4.x;
            zs[lc4 * 4 + 1][lrow] = t4.y;
            zs[lc4 * 4 + 2][lrow] = t4.z;
            zs[lc4 * 4 + 3][lrow] = t4.w;
            // e tile: 64 codes x 32 k, transposed to [k][code]
            float4 e4 = *reinterpret_cast<const float4*>(&eb[(size_t)lrow * DD + kk + lc4 * 4]);
            es[lc4 * 4 + 0][lrow] = e4.x;
            es[lc4 * 4 + 1][lrow] = e4.y;
            es[lc4 * 4 + 2][lrow] = e4.z;
            es[lc4 * 4 + 3][lrow] = e4.w;
        }
        __syncthreads();
#pragma unroll
        for (int k = 0; k < 32; ++k) {
            float2 zv = *reinterpret_cast<const float2*>(&zs[k][ty * 2]);
            float4 ev = *reinterpret_cast<const float4*>(&es[k][tx * 4]);
            double z0 = (double)zv.x, z1 = (double)zv.y;
            double e0 = (double)ev.x, e1 = (double)ev.y;
            double e2d = (double)ev.z, e3 = (double)ev.w;
            acc[0][0] = fma(z0, e0, acc[0][0]);
            acc[0][1] = fma(z0, e1, acc[0][1]);
            acc[0][2] = fma(z0, e2d, acc[0][2]);
            acc[0][3] = fma(z0, e3, acc[0][3]);
            acc[1][0] = fma(z1, e0, acc[1][0]);
            acc[1][1] = fma(z1, e1, acc[1][1]);
            acc[1][2] = fma(z1, e2d, acc[1][2]);
            acc[1][3] = fma(z1, e3, acc[1][3]);
        }
    }

    // scores s = e2[code] - 2*dot ; local argmin over 4 codes (first-index)
    double e2v[4];
#pragma unroll
    for (int j = 0; j < 4; ++j) e2v[j] = e2[b * NE + tx * 4 + j];

    double vmin[2]; int imin[2];
#pragma unroll
    for (int r = 0; r < 2; ++r) {
        vmin[r] = e2v[0] - 2.0 * acc[r][0];
        imin[r] = tx * 4;
#pragma unroll
        for (int j = 1; j < 4; ++j) {
            double s = e2v[j] - 2.0 * acc[r][j];
            if (s < vmin[r]) { vmin[r] = s; imin[r] = tx * 4 + j; }
        }
    }
    // butterfly over the 16 tx lanes (stays within wave: tx = lane&15)
#pragma unroll
    for (int off = 1; off < 16; off <<= 1) {
#pragma unroll
        for (int r = 0; r < 2; ++r) {
            double ov = __shfl_xor(vmin[r], off);
            int    oi = __shfl_xor(imin[r], off);
            if (ov < vmin[r] || (ov == vmin[r] && oi < imin[r])) { vmin[r] = ov; imin[r] = oi; }
        }
    }
    if (tid < 64) cnt_s[tid] = 0;
    if (tx == 0) { kms[ty * 2] = imin[0]; kms[ty * 2 + 1] = imin[1]; }
    __syncthreads();
    if (tid < 64) atomicAdd(&cnt_s[kms[tid]], 1);

    // ---------------- phase 2: zq / enc / idx / loss ----------------
    const int row = tid >> 3, p = tid & 7;
    const int km  = kms[row];
    const float* zr = &zb[(size_t)row * DD];
    const float* er = &eb[(size_t)km * DD];
    const size_t grow = (size_t)b * TTOK + m0 + row;
    float* zqr = zq + grow * DD;
    double lsum = 0.0;
#pragma unroll 4
    for (int i = 0; i < 16; ++i) {
        int col = (i * 8 + p) * 4;
        float4 zv = *reinterpret_cast<const float4*>(&zr[col]);
        float4 ev = *reinterpret_cast<const float4*>(&er[col]);
        float d0 = ev.x - zv.x, d1 = ev.y - zv.y, d2 = ev.z - zv.z, d3 = ev.w - zv.w;
        lsum += (double)d0 * d0 + (double)d1 * d1 + (double)d2 * d2 + (double)d3 * d3;
        float4 o4 = {zv.x + d0, zv.y + d1, zv.z + d2, zv.w + d3};
        *reinterpret_cast<float4*>(&zqr[col]) = o4;
    }
    // enc one-hot: thread writes codes p*8 .. p*8+7 of its row
    {
        float* ep = enc + grow * NE + p * 8;
        float4 o0, o1;
        o0.x = (p * 8 + 0 == km) ? 1.f : 0.f;
        o0.y = (p * 8 + 1 == km) ? 1.f : 0.f;
        o0.z = (p * 8 + 2 == km) ? 1.f : 0.f;
        o0.w = (p * 8 + 3 == km) ? 1.f : 0.f;
        o1.x = (p * 8 + 4 == km) ? 1.f : 0.f;
        o1.y = (p * 8 + 5 == km) ? 1.f : 0.f;
        o1.z = (p * 8 + 6 == km) ? 1.f : 0.f;
        o1.w = (p * 8 + 7 == km) ? 1.f : 0.f;
        *reinterpret_cast<float4*>(ep)     = o0;
        *reinterpret_cast<float4*>(ep + 4) = o1;
    }
    if (tid < 64) idxo[(size_t)b * TTOK + m0 + tid] = (float)kms[tid];

    // deterministic loss reduce (8 waves)
#pragma unroll
    for (int off = 32; off; off >>= 1) lsum += __shfl_down(lsum, off);
    if ((tid & 63) == 0) dred[tid >> 6] = lsum;
    __syncthreads();
    if (tid == 0) {
        double t = 0.0;
#pragma unroll
        for (int w = 0; w < 8; ++w) t += dred[w];
        lossp[bid] = t;
    }
    if (tid < 64 && cnt_s[tid]) atomicAdd(&counts[tid], cnt_s[tid]);
}

// =======================================================================
// Finalize: loss (sequential f64 sum of 512 partials) + perplexity
// =======================================================================
__global__ void fin_k(const double* __restrict__ lossp, const int* __restrict__ counts,
                      float* __restrict__ loss_out, float* __restrict__ perp_out)
{
    int tid = threadIdx.x;  // 64 threads
    if (tid == 0) {
        double tot = 0.0;
        for (int i = 0; i < 512; ++i) tot += lossp[i];
        loss_out[0] = (float)(1.5 * tot / 16777216.0);   // (BETA+1)*mean
    }
    float e = counts[tid] / 32768.0f;
    float term = e * logf(e + 1e-10f);
#pragma unroll
    for (int off = 32; off; off >>= 1) term += __shfl_down(term, off);
    if (tid == 0) perp_out[0] = expf(-term);
}

// =======================================================================
extern "C" void kernel_launch(void* const* d_in, const int* in_sizes, int n_in,
                              void* d_out, int out_size, void* d_ws, size_t ws_size,
                              hipStream_t stream)
{
    (void)in_sizes; (void)n_in; (void)out_size; (void)ws_size;
    const float* x_enc = (const float*)d_in[0];
    const float* z     = (const float*)d_in[1];
    const float* tab   = (const float*)d_in[2];
    const float* wq1 = (const float*)d_in[3];  const float* bq1 = (const float*)d_in[4];
    const float* wk1 = (const float*)d_in[5];  const float* bk1 = (const float*)d_in[6];
    const float* wv1 = (const float*)d_in[7];  const float* bv1 = (const float*)d_in[8];
    const float* wo1 = (const float*)d_in[9];  const float* bo1 = (const float*)d_in[10];
    const float* wq2 = (const float*)d_in[11]; const float* bq2 = (const float*)d_in[12];
    const float* wk2 = (const float*)d_in[13]; const float* bk2 = (const float*)d_in[14];
    const float* wv2 = (const float*)d_in[15]; const float* bv2 = (const float*)d_in[16];
    const float* wo2 = (const float*)d_in[17]; const float* bo2 = (const float*)d_in[18];
    const float* ln2g = (const float*)d_in[19]; const float* ln2b = (const float*)d_in[20];
    const float* ln1g = (const float*)d_in[21]; const float* ln1b = (const float*)d_in[22];

    float* ws  = (float*)d_ws;
    float* out = (float*)d_out;

    float* k1   = ws + WS_K1;
    float* v1   = ws + WS_V1;
    float* emb0 = ws + WS_EMB0;
    float* q1   = ws + WS_Q1;
    float* att1 = ws + WS_ATT1;
    float* emb1 = ws + WS_EMB1;
    float* q2   = ws + WS_Q2;
    float* k2   = ws + WS_K2;
    float* v2   = ws + WS_V2;
    float* att2 = ws + WS_ATT2;
    float* ybuf = ws + WS_YBUF;
    float* embf = ws + WS_EMBF;
    double* e2    = (double*)(ws + WS_E2);
    double* lossp = (double*)(ws + WS_LOSSP);
    int*    cnts  = (int*)(ws + WS_CNT);

    hipMemsetAsync(cnts, 0, NE * sizeof(int), stream);

    pe_emb0_k<<<64, 256, 0, stream>>>(tab, emb0);

    gemm_bias_k<1><<<dim3(1, 8), 256, 0, stream>>>(emb0, wq1, bq1, q1,
                                                   nullptr, nullptr, nullptr,
                                                   nullptr, nullptr, nullptr);
    gemm_bias_k<2><<<dim3(256, 8), 256, 0, stream>>>(x_enc, wk1, bk1, k1,
                                                     wv1, bv1, v1,
                                                     nullptr, nullptr, nullptr);
    attn_k<<<128, 256, 0, stream>>>(q1, 1, k1, v1, att1, SENC);

    gemm_bias_k<1><<<dim3(16, 8), 256, 0, stream>>>(att1, wo1, bo1, ybuf,
                                                    nullptr, nullptr, nullptr,
                                                    nullptr, nullptr, nullptr);
    ln_k<<<1024, 256, 0, stream>>>(emb0, 1, ybuf, ln1g, ln1b, emb1, nullptr, nullptr);

    gemm_bias_k<3><<<dim3(16, 8), 256, 0, stream>>>(emb1, wq2, bq2, q2,
                                                    wk2, bk2, k2,
                                                    wv2, bv2, v2);
    attn_k<<<128, 256, 0, stream>>>(q2, 0, k2, v2, att2, 64);

    gemm_bias_k<1><<<dim3(16, 8), 256, 0, stream>>>(att2, wo2, bo2, ybuf,
                                                    nullptr, nullptr, nullptr,
                                                    nullptr, nullptr, nullptr);
    ln_k<<<1024, 256, 0, stream>>>(emb1, 0, ybuf, ln2g, ln2b, embf, out + OUT_EMB, e2);

    vq_k<<<512, 512, 0, stream>>>(z, embf, e2,
                                  out + OUT_ZQ, out + OUT_ENC, out + OUT_IDX,
                                  lossp, cnts);
    fin_k<<<1, 64, 0, stream>>>(lossp, cnts, out + OUT_LOSS, out + OUT_PERP);
}